// Round 8
// baseline (276.438 us; speedup 1.0000x reference)
//
#include <hip/hip_runtime.h>
#include <hip/hip_bf16.h>

// Problem constants (from reference)
#define DIMX   768
#define HEADS  12
#define DH     64
#define INNER  768
#define NQKV   2304
#define SEQ    4096
#define BATCH  2
#define ROWS   (BATCH*SEQ)   // 8192
#define EPSF   1e-8f
#define LOG2E  1.4426950408889634f

typedef __bf16 bf16x8 __attribute__((ext_vector_type(8)));
typedef float  f32x4  __attribute__((ext_vector_type(4)));
typedef float  f32x16 __attribute__((ext_vector_type(16)));

// RNE f32 -> bf16 (finite inputs only)
__device__ __forceinline__ unsigned short f2bf(float f) {
    unsigned int u = __float_as_uint(f);
    unsigned int r = ((u >> 16) & 1u) + 0x7FFFu;
    return (unsigned short)((u + r) >> 16);
}
__device__ __forceinline__ float bf2f(unsigned short u) {
    return __builtin_bit_cast(float, (unsigned)u << 16);
}
// pack two f32 into a u32 of 2 bf16 (lo = a, hi = b) via native casts
__device__ __forceinline__ unsigned pkbf(float a, float b) {
    unsigned short la = __builtin_bit_cast(unsigned short, (__bf16)a);
    unsigned short lb = __builtin_bit_cast(unsigned short, (__bf16)b);
    return (unsigned)la | ((unsigned)lb << 16);
}

// async global->LDS, 16B per lane: dest = ldsbase + lane*16 (wave-uniform base),
// source is per-lane. [guide §5: global_load_lds caveat m104/m173]
__device__ __forceinline__ void gload_lds16(const void* g, void* l) {
    __builtin_amdgcn_global_load_lds(
        (const __attribute__((address_space(1))) void*)g,
        (__attribute__((address_space(3))) void*)l, 16, 0, 0);
}

__global__ __launch_bounds__(256) void cast_f32_bf16(
    const float* __restrict__ src, unsigned short* __restrict__ dst, int n)
{
    int i = (blockIdx.x * 256 + threadIdx.x) * 4;
    if (i + 3 < n) {
        float4 v = *reinterpret_cast<const float4*>(src + i);
        ushort4 o;
        o.x = f2bf(v.x); o.y = f2bf(v.y); o.z = f2bf(v.z); o.w = f2bf(v.w);
        *reinterpret_cast<ushort4*>(dst + i) = o;
    }
}

// C[M][N] = A[M][K] (bf16) * B[N][K]^T (bf16) (+ bias); out f32 or bf16.
// m97-style staging: unpadded [128][64] LDS, global_load_lds width 16.
// Each wave stages rows [wid*32, wid*32+32) of A and B: 4 slabs x 8 rows,
// slab = 1024 B = 64 lanes x 16B; lane l covers row +l/8, col (l&7)*8.
template<bool BF16OUT>
__global__ __launch_bounds__(256) void gemm_bt_kernel(
    const unsigned short* __restrict__ A,
    const unsigned short* __restrict__ B,
    void* __restrict__ Cv,
    const float* __restrict__ bias,
    int M, int N, int K)
{
    __shared__ unsigned short shA[128][64];
    __shared__ unsigned short shB[128][64];

    const int bm0 = blockIdx.x * 128;
    const int bn0 = blockIdx.y * 128;
    const int tid = threadIdx.x;
    const int lane = tid & 63;
    const int wid  = tid >> 6;
    const int l15  = lane & 15;
    const int l4   = lane >> 4;
    const int wr   = wid >> 1;
    const int wc   = wid & 1;
    const int srow = lane >> 3;        // 0..7 within slab
    const int scol = (lane & 7) * 8;   // elem col

    f32x4 acc[4][4];
    #pragma unroll
    for (int i = 0; i < 4; ++i)
        #pragma unroll
        for (int j = 0; j < 4; ++j)
            acc[i][j] = (f32x4){0.f, 0.f, 0.f, 0.f};

    const int nkt = K >> 6;
    for (int kt = 0; kt < nkt; ++kt) {
        const int k0 = kt << 6;
        __syncthreads();
        #pragma unroll
        for (int j = 0; j < 4; ++j) {
            int row = wid * 32 + j * 8;
            gload_lds16(&A[(size_t)(bm0 + row + srow) * K + k0 + scol], &shA[row][0]);
            gload_lds16(&B[(size_t)(bn0 + row + srow) * K + k0 + scol], &shB[row][0]);
        }
        __syncthreads();   // compiler drains vmcnt before this barrier
        #pragma unroll
        for (int ks = 0; ks < 2; ++ks) {
            bf16x8 af[4], bfr[4];
            #pragma unroll
            for (int mf = 0; mf < 4; ++mf)
                af[mf] = *reinterpret_cast<const bf16x8*>(&shA[wr * 64 + mf * 16 + l15][ks * 32 + l4 * 8]);
            #pragma unroll
            for (int nf = 0; nf < 4; ++nf)
                bfr[nf] = *reinterpret_cast<const bf16x8*>(&shB[wc * 64 + nf * 16 + l15][ks * 32 + l4 * 8]);
            #pragma unroll
            for (int mf = 0; mf < 4; ++mf)
                #pragma unroll
                for (int nf = 0; nf < 4; ++nf)
                    acc[mf][nf] = __builtin_amdgcn_mfma_f32_16x16x32_bf16(
                        af[mf], bfr[nf], acc[mf][nf], 0, 0, 0);
        }
    }

    #pragma unroll
    for (int mf = 0; mf < 4; ++mf) {
        #pragma unroll
        for (int nf = 0; nf < 4; ++nf) {
            int col = bn0 + wc * 64 + nf * 16 + l15;
            float badd = bias ? bias[col] : 0.f;
            #pragma unroll
            for (int r = 0; r < 4; ++r) {
                int row = bm0 + wr * 64 + mf * 16 + l4 * 4 + r;
                if constexpr (BF16OUT)
                    ((unsigned short*)Cv)[(size_t)row * N + col] = f2bf(acc[mf][nf][r] + badd);
                else
                    ((float*)Cv)[(size_t)row * N + col] = acc[mf][nf][r] + badd;
            }
        }
    }
}

// Cross-head L2 norm on bf16 qkv; Q scaled by log2e/scale[h]. q,k only.
__global__ __launch_bounds__(256) void normalize_kernel(
    const unsigned short* __restrict__ qkv,
    const float* __restrict__ scale,
    unsigned short* __restrict__ qo,
    unsigned short* __restrict__ ko)
{
    int t = blockIdx.x * 256 + threadIdx.x;
    int row = t >> 6;
    int d = t & 63;
    int b = row >> 12;
    int n = row & 4095;
    const unsigned short* base = qkv + (size_t)row * NQKV;

    float qv[12], kv[12];
    float sq = 0.f, sk = 0.f;
    #pragma unroll
    for (int h = 0; h < 12; ++h) {
        qv[h] = bf2f(base[h * 64 + d]);
        kv[h] = bf2f(base[768 + h * 64 + d]);
        sq += qv[h] * qv[h];
        sk += kv[h] * kv[h];
    }
    float rq = rsqrtf(sqrtf(sq) + EPSF);
    float rk = rsqrtf(sqrtf(sk) + EPSF);
    #pragma unroll
    for (int h = 0; h < 12; ++h) {
        size_t bh = (size_t)(b * 12 + h);
        float fold = LOG2E / scale[h];
        qo[(bh * SEQ + n) * 64 + d] = f2bf(qv[h] * rq * fold);
        ko[(bh * SEQ + n) * 64 + d] = f2bf(kv[h] * rk);
    }
}

// V transpose: qkv bf16 v-part [b,n,h,d] -> vt [bh][d][n], coalesced both ways
// via a 64x64 LDS tile. Grid: (BATCH*HEADS, SEQ/64).
__global__ __launch_bounds__(256) void vtrans_kernel(
    const unsigned short* __restrict__ qkv,
    unsigned short* __restrict__ vt)
{
    __shared__ unsigned short tile[64][72];
    const int bh = blockIdx.x;
    const int nt = blockIdx.y;
    const int b = bh / HEADS, h = bh % HEADS;
    const int tid = threadIdx.x;

    #pragma unroll
    for (int it = 0; it < 2; ++it) {
        int c = tid + it * 256;
        int r = c >> 3, cc = c & 7;
        *reinterpret_cast<uint4*>(&tile[r][cc * 8]) =
            *reinterpret_cast<const uint4*>(
                &qkv[(size_t)(b * SEQ + nt * 64 + r) * NQKV + 1536 + h * 64 + cc * 8]);
    }
    __syncthreads();
    #pragma unroll
    for (int it = 0; it < 2; ++it) {
        int c = tid + it * 256;
        int d = c >> 3, nc = c & 7;
        ushort4 o0, o1;
        o0.x = tile[nc * 8 + 0][d]; o0.y = tile[nc * 8 + 1][d];
        o0.z = tile[nc * 8 + 2][d]; o0.w = tile[nc * 8 + 3][d];
        o1.x = tile[nc * 8 + 4][d]; o1.y = tile[nc * 8 + 5][d];
        o1.z = tile[nc * 8 + 6][d]; o1.w = tile[nc * 8 + 7][d];
        unsigned short* dst = &vt[((size_t)bh * 64 + d) * SEQ + nt * 64 + nc * 8];
        *reinterpret_cast<ushort4*>(dst)     = o0;
        *reinterpret_cast<ushort4*>(dst + 4) = o1;
    }
}

// Flash attention, no-max softmax (scores bounded after scale/log2e fold).
// Double-buffered LDS + register prefetch (T14/T3-min): issue next tile's
// global loads right after the single per-tile barrier, compute current tile,
// then ds_write the regs into the other buffer. ONE barrier per tile; loads
// have the whole compute phase to land (no exposed vmcnt(0) stall).
// 4 waves / 256 threads; q = lane&31 lane-local throughout.
__global__ __launch_bounds__(256) void attn_kernel(
    const unsigned short* __restrict__ qg,
    const unsigned short* __restrict__ kg,
    const unsigned short* __restrict__ vtg,
    unsigned short* __restrict__ attnout)
{
    __shared__ unsigned short shK[2][64][72];   // [buf][kv][d]
    __shared__ unsigned short shV[2][64][72];   // [buf][d][kv]  (V^T)

    const int qblk = blockIdx.x;
    const int bh   = blockIdx.y;
    const int b    = bh / HEADS;
    const int h    = bh % HEADS;
    const int tid  = threadIdx.x;
    const int lane = tid & 63;
    const int wid  = tid >> 6;
    const int l31  = lane & 31;
    const int hi   = lane >> 5;
    // staging coords: thread covers rows r0 and r0+32, col sc (8 elems)
    const int r0 = tid >> 3;          // 0..31
    const int sc = (tid & 7) * 8;

    // Q fragments (B operand, col=q=l31, k = d0*16 + hi*8 + j)
    bf16x8 qf[4];
    {
        const unsigned short* qrow =
            qg + ((size_t)bh * SEQ + qblk * 128 + wid * 32 + l31) * 64 + hi * 8;
        #pragma unroll
        for (int d0 = 0; d0 < 4; ++d0)
            qf[d0] = *reinterpret_cast<const bf16x8*>(qrow + d0 * 16);
    }

    f32x16 ot[2];
    #pragma unroll
    for (int r = 0; r < 16; ++r) { ot[0][r] = 0.f; ot[1][r] = 0.f; }
    float l_lane = 0.f;

    const unsigned short* kbase = kg  + (size_t)bh * SEQ * 64;
    const unsigned short* vbase = vtg + (size_t)bh * 64 * SEQ;

    // prologue: load tile 0 into regs, write buf 0
    uint4 rk0 = *reinterpret_cast<const uint4*>(&kbase[(size_t)r0 * 64 + sc]);
    uint4 rk1 = *reinterpret_cast<const uint4*>(&kbase[(size_t)(32 + r0) * 64 + sc]);
    uint4 rv0 = *reinterpret_cast<const uint4*>(&vbase[(size_t)r0 * SEQ + sc]);
    uint4 rv1 = *reinterpret_cast<const uint4*>(&vbase[(size_t)(32 + r0) * SEQ + sc]);
    *reinterpret_cast<uint4*>(&shK[0][r0][sc])      = rk0;
    *reinterpret_cast<uint4*>(&shK[0][32 + r0][sc]) = rk1;
    *reinterpret_cast<uint4*>(&shV[0][r0][sc])      = rv0;
    *reinterpret_cast<uint4*>(&shV[0][32 + r0][sc]) = rv1;

    for (int kt = 0; kt < SEQ / 64; ++kt) {
        const int cur = kt & 1;
        __syncthreads();   // buf[cur] written; prev reads of buf[cur^1] done

        if (kt < SEQ / 64 - 1) {   // issue next tile's loads (land during compute)
            const unsigned short* kn = kbase + (size_t)(kt + 1) * 64 * 64;
            const unsigned short* vn = vbase + (size_t)(kt + 1) * 64;
            rk0 = *reinterpret_cast<const uint4*>(&kn[(size_t)r0 * 64 + sc]);
            rk1 = *reinterpret_cast<const uint4*>(&kn[(size_t)(32 + r0) * 64 + sc]);
            rv0 = *reinterpret_cast<const uint4*>(&vn[(size_t)r0 * SEQ + sc]);
            rv1 = *reinterpret_cast<const uint4*>(&vn[(size_t)(32 + r0) * SEQ + sc]);
        }

        // ---- S^T = K * Q^T (exp2 domain: scale folded into Q) ----
        f32x16 st0, st1;
        #pragma unroll
        for (int r = 0; r < 16; ++r) { st0[r] = 0.f; st1[r] = 0.f; }
        #pragma unroll
        for (int d0 = 0; d0 < 4; ++d0) {
            bf16x8 kf0 = *reinterpret_cast<const bf16x8*>(&shK[cur][l31][d0 * 16 + hi * 8]);
            bf16x8 kf1 = *reinterpret_cast<const bf16x8*>(&shK[cur][32 + l31][d0 * 16 + hi * 8]);
            st0 = __builtin_amdgcn_mfma_f32_32x32x16_bf16(kf0, qf[d0], st0, 0, 0, 0);
            st1 = __builtin_amdgcn_mfma_f32_32x32x16_bf16(kf1, qf[d0], st1, 0, 0, 0);
        }

        // ---- P = exp2(S), no max shift (scores bounded); pack bf16 pairs ----
        float s0 = 0.f, s1 = 0.f, s2 = 0.f, s3 = 0.f;
        unsigned cp0[8], cp1[8];
        #pragma unroll
        for (int t = 0; t < 8; ++t) {
            float pa = __builtin_amdgcn_exp2f(st0[2 * t]);
            float pb = __builtin_amdgcn_exp2f(st0[2 * t + 1]);
            float pc = __builtin_amdgcn_exp2f(st1[2 * t]);
            float pd = __builtin_amdgcn_exp2f(st1[2 * t + 1]);
            s0 += pa; s1 += pb; s2 += pc; s3 += pd;
            cp0[t] = pkbf(pa, pb);
            cp1[t] = pkbf(pc, pd);
        }
        l_lane += (s0 + s1) + (s2 + s3);

        // ---- O^T += V^T * P^T (cross-half exchange via shfl_xor + select) ----
        #pragma unroll
        for (int cb = 0; cb < 2; ++cb) {
            #pragma unroll
            for (int kk = 0; kk < 2; ++kk) {
                unsigned c0 = cb ? cp1[4 * kk + 0] : cp0[4 * kk + 0];
                unsigned c1 = cb ? cp1[4 * kk + 1] : cp0[4 * kk + 1];
                unsigned c2 = cb ? cp1[4 * kk + 2] : cp0[4 * kk + 2];
                unsigned c3 = cb ? cp1[4 * kk + 3] : cp0[4 * kk + 3];
                unsigned e0 = __shfl_xor(c0, 32);
                unsigned e1 = __shfl_xor(c1, 32);
                unsigned e2 = __shfl_xor(c2, 32);
                unsigned e3 = __shfl_xor(c3, 32);
                union { unsigned uu[4]; bf16x8 v; } pu;
                pu.uu[0] = hi ? e2 : c0;
                pu.uu[1] = hi ? e3 : c1;
                pu.uu[2] = hi ? c2 : e0;
                pu.uu[3] = hi ? c3 : e1;
                #pragma unroll
                for (int df = 0; df < 2; ++df) {
                    bf16x8 vf = *reinterpret_cast<const bf16x8*>(
                        &shV[cur][df * 32 + l31][cb * 32 + kk * 16 + hi * 8]);
                    ot[df] = __builtin_amdgcn_mfma_f32_32x32x16_bf16(vf, pu.v, ot[df], 0, 0, 0);
                }
            }
        }

        // ---- write prefetched tile into the other buffer ----
        if (kt < SEQ / 64 - 1) {
            *reinterpret_cast<uint4*>(&shK[cur ^ 1][r0][sc])      = rk0;
            *reinterpret_cast<uint4*>(&shK[cur ^ 1][32 + r0][sc]) = rk1;
            *reinterpret_cast<uint4*>(&shV[cur ^ 1][r0][sc])      = rv0;
            *reinterpret_cast<uint4*>(&shV[cur ^ 1][32 + r0][sc]) = rv1;
        }
    }

    // ---- epilogue: O[q][d] = O^T[d][q] / l, q = l31 lane-local ----
    float l_all = l_lane + __shfl_xor(l_lane, 32);
    float invl = 1.0f / l_all;
    int n = qblk * 128 + wid * 32 + l31;
    unsigned short* orow = attnout + ((size_t)(b * SEQ + n)) * INNER + h * 64;
    #pragma unroll
    for (int df = 0; df < 2; ++df) {
        #pragma unroll
        for (int t = 0; t < 4; ++t) {
            unsigned w0 = pkbf(ot[df][4 * t]     * invl, ot[df][4 * t + 1] * invl);
            unsigned w1 = pkbf(ot[df][4 * t + 2] * invl, ot[df][4 * t + 3] * invl);
            unsigned long long pk = (unsigned long long)w0 | ((unsigned long long)w1 << 32);
            *reinterpret_cast<unsigned long long*>(orow + df * 32 + t * 8 + hi * 4) = pk;
        }
    }
}

extern "C" void kernel_launch(void* const* d_in, const int* in_sizes, int n_in,
                              void* d_out, int out_size, void* d_ws, size_t ws_size,
                              hipStream_t stream)
{
    const float* x      = (const float*)d_in[0];
    const float* w_qkv  = (const float*)d_in[1];
    const float* w_out  = (const float*)d_in[2];
    const float* b_out  = (const float*)d_in[3];
    const float* scale  = (const float*)d_in[4];
    float* out = (float*)d_out;
    char* ws = (char*)d_ws;

    unsigned short* xb    = (unsigned short*)(ws);                 // 12,582,912
    unsigned short* wqkvb = (unsigned short*)(ws + 12582912);      //  3,538,944
    unsigned short* woutb = (unsigned short*)(ws + 16121856);      //  1,179,648
    unsigned short* attnb = (unsigned short*)(ws + 17301504);      // 12,582,912
    unsigned short* qb    = (unsigned short*)(ws + 29884416);      // 12,582,912
    unsigned short* kb    = (unsigned short*)(ws + 42467328);      // 12,582,912
    unsigned short* vtb   = (unsigned short*)(ws + 55050240);      // 12,582,912
    unsigned short* qkvb  = (unsigned short*)(ws + 67633152);      // 37,748,736

    cast_f32_bf16<<<6144, 256, 0, stream>>>(x, xb, 6291456);
    cast_f32_bf16<<<1728, 256, 0, stream>>>(w_qkv, wqkvb, 1769472);
    cast_f32_bf16<<<576, 256, 0, stream>>>(w_out, woutb, 589824);

    gemm_bt_kernel<true><<<dim3(64, 18), 256, 0, stream>>>(xb, wqkvb, qkvb, nullptr, ROWS, NQKV, DIMX);

    normalize_kernel<<<2048, 256, 0, stream>>>(qkvb, scale, qb, kb);
    vtrans_kernel<<<dim3(BATCH * HEADS, SEQ / 64), 256, 0, stream>>>(qkvb, vtb);

    attn_kernel<<<dim3(SEQ / 128, BATCH * HEADS), 256, 0, stream>>>(qb, kb, vtb, attnb);

    gemm_bt_kernel<false><<<dim3(64, 6), 256, 0, stream>>>(attnb, woutb, out, b_out, ROWS, INNER, INNER);
}

// Round 9
// 255.510 us; speedup vs baseline: 1.0819x; 1.0819x over previous
//
#include <hip/hip_runtime.h>
#include <hip/hip_bf16.h>

// Problem constants (from reference)
#define DIMX   768
#define HEADS  12
#define DH     64
#define INNER  768
#define NQKV   2304
#define SEQ    4096
#define BATCH  2
#define ROWS   (BATCH*SEQ)   // 8192
#define EPSF   1e-8f
#define LOG2E  1.4426950408889634f

typedef __bf16 bf16x8 __attribute__((ext_vector_type(8)));
typedef float  f32x4  __attribute__((ext_vector_type(4)));
typedef float  f32x16 __attribute__((ext_vector_type(16)));
typedef unsigned u32x2 __attribute__((ext_vector_type(2)));

// RNE f32 -> bf16 (finite inputs only)
__device__ __forceinline__ unsigned short f2bf(float f) {
    unsigned int u = __float_as_uint(f);
    unsigned int r = ((u >> 16) & 1u) + 0x7FFFu;
    return (unsigned short)((u + r) >> 16);
}
__device__ __forceinline__ float bf2f(unsigned short u) {
    return __builtin_bit_cast(float, (unsigned)u << 16);
}
// pack two f32 into a u32 of 2 bf16 (lo = a, hi = b) via native casts
// (compiles to v_cvt_pk_bf16_f32; proven rounds 3-8)
__device__ __forceinline__ unsigned pkbf(float a, float b) {
    unsigned short la = __builtin_bit_cast(unsigned short, (__bf16)a);
    unsigned short lb = __builtin_bit_cast(unsigned short, (__bf16)b);
    return (unsigned)la | ((unsigned)lb << 16);
}

// async global->LDS, 16B per lane: dest = ldsbase + lane*16 (wave-uniform base)
__device__ __forceinline__ void gload_lds16(const void* g, void* l) {
    __builtin_amdgcn_global_load_lds(
        (const __attribute__((address_space(1))) void*)g,
        (__attribute__((address_space(3))) void*)l, 16, 0, 0);
}

__global__ __launch_bounds__(256) void cast_f32_bf16(
    const float* __restrict__ src, unsigned short* __restrict__ dst, int n)
{
    int i = (blockIdx.x * 256 + threadIdx.x) * 4;
    if (i + 3 < n) {
        float4 v = *reinterpret_cast<const float4*>(src + i);
        ushort4 o;
        o.x = f2bf(v.x); o.y = f2bf(v.y); o.z = f2bf(v.z); o.w = f2bf(v.w);
        *reinterpret_cast<ushort4*>(dst + i) = o;
    }
}

// C[M][N] = A[M][K] (bf16) * B[N][K]^T (bf16) (+ bias); out f32 or bf16.
// m97-style staging: unpadded [128][64] LDS, global_load_lds width 16.
template<bool BF16OUT>
__global__ __launch_bounds__(256) void gemm_bt_kernel(
    const unsigned short* __restrict__ A,
    const unsigned short* __restrict__ B,
    void* __restrict__ Cv,
    const float* __restrict__ bias,
    int M, int N, int K)
{
    __shared__ unsigned short shA[128][64];
    __shared__ unsigned short shB[128][64];

    const int bm0 = blockIdx.x * 128;
    const int bn0 = blockIdx.y * 128;
    const int tid = threadIdx.x;
    const int lane = tid & 63;
    const int wid  = tid >> 6;
    const int l15  = lane & 15;
    const int l4   = lane >> 4;
    const int wr   = wid >> 1;
    const int wc   = wid & 1;
    const int srow = lane >> 3;        // 0..7 within slab
    const int scol = (lane & 7) * 8;   // elem col

    f32x4 acc[4][4];
    #pragma unroll
    for (int i = 0; i < 4; ++i)
        #pragma unroll
        for (int j = 0; j < 4; ++j)
            acc[i][j] = (f32x4){0.f, 0.f, 0.f, 0.f};

    const int nkt = K >> 6;
    for (int kt = 0; kt < nkt; ++kt) {
        const int k0 = kt << 6;
        __syncthreads();
        #pragma unroll
        for (int j = 0; j < 4; ++j) {
            int row = wid * 32 + j * 8;
            gload_lds16(&A[(size_t)(bm0 + row + srow) * K + k0 + scol], &shA[row][0]);
            gload_lds16(&B[(size_t)(bn0 + row + srow) * K + k0 + scol], &shB[row][0]);
        }
        __syncthreads();
        #pragma unroll
        for (int ks = 0; ks < 2; ++ks) {
            bf16x8 af[4], bfr[4];
            #pragma unroll
            for (int mf = 0; mf < 4; ++mf)
                af[mf] = *reinterpret_cast<const bf16x8*>(&shA[wr * 64 + mf * 16 + l15][ks * 32 + l4 * 8]);
            #pragma unroll
            for (int nf = 0; nf < 4; ++nf)
                bfr[nf] = *reinterpret_cast<const bf16x8*>(&shB[wc * 64 + nf * 16 + l15][ks * 32 + l4 * 8]);
            #pragma unroll
            for (int mf = 0; mf < 4; ++mf)
                #pragma unroll
                for (int nf = 0; nf < 4; ++nf)
                    acc[mf][nf] = __builtin_amdgcn_mfma_f32_16x16x32_bf16(
                        af[mf], bfr[nf], acc[mf][nf], 0, 0, 0);
        }
    }

    #pragma unroll
    for (int mf = 0; mf < 4; ++mf) {
        #pragma unroll
        for (int nf = 0; nf < 4; ++nf) {
            int col = bn0 + wc * 64 + nf * 16 + l15;
            float badd = bias ? bias[col] : 0.f;
            #pragma unroll
            for (int r = 0; r < 4; ++r) {
                int row = bm0 + wr * 64 + mf * 16 + l4 * 4 + r;
                if constexpr (BF16OUT)
                    ((unsigned short*)Cv)[(size_t)row * N + col] = f2bf(acc[mf][nf][r] + badd);
                else
                    ((float*)Cv)[(size_t)row * N + col] = acc[mf][nf][r] + badd;
            }
        }
    }
}

// Cross-head L2 norm on bf16 qkv; Q scaled by log2e/scale[h]. q,k only.
__global__ __launch_bounds__(256) void normalize_kernel(
    const unsigned short* __restrict__ qkv,
    const float* __restrict__ scale,
    unsigned short* __restrict__ qo,
    unsigned short* __restrict__ ko)
{
    int t = blockIdx.x * 256 + threadIdx.x;
    int row = t >> 6;
    int d = t & 63;
    int b = row >> 12;
    int n = row & 4095;
    const unsigned short* base = qkv + (size_t)row * NQKV;

    float qv[12], kv[12];
    float sq = 0.f, sk = 0.f;
    #pragma unroll
    for (int h = 0; h < 12; ++h) {
        qv[h] = bf2f(base[h * 64 + d]);
        kv[h] = bf2f(base[768 + h * 64 + d]);
        sq += qv[h] * qv[h];
        sk += kv[h] * kv[h];
    }
    float rq = rsqrtf(sqrtf(sq) + EPSF);
    float rk = rsqrtf(sqrtf(sk) + EPSF);
    #pragma unroll
    for (int h = 0; h < 12; ++h) {
        size_t bh = (size_t)(b * 12 + h);
        float fold = LOG2E / scale[h];
        qo[(bh * SEQ + n) * 64 + d] = f2bf(qv[h] * rq * fold);
        ko[(bh * SEQ + n) * 64 + d] = f2bf(kv[h] * rk);
    }
}

// V transpose: qkv bf16 v-part [b,n,h,d] -> vt [bh][d][n], coalesced both ways
// via a 64x64 LDS tile. Grid: (BATCH*HEADS, SEQ/64).
__global__ __launch_bounds__(256) void vtrans_kernel(
    const unsigned short* __restrict__ qkv,
    unsigned short* __restrict__ vt)
{
    __shared__ unsigned short tile[64][72];
    const int bh = blockIdx.x;
    const int nt = blockIdx.y;
    const int b = bh / HEADS, h = bh % HEADS;
    const int tid = threadIdx.x;

    #pragma unroll
    for (int it = 0; it < 2; ++it) {
        int c = tid + it * 256;
        int r = c >> 3, cc = c & 7;
        *reinterpret_cast<uint4*>(&tile[r][cc * 8]) =
            *reinterpret_cast<const uint4*>(
                &qkv[(size_t)(b * SEQ + nt * 64 + r) * NQKV + 1536 + h * 64 + cc * 8]);
    }
    __syncthreads();
    #pragma unroll
    for (int it = 0; it < 2; ++it) {
        int c = tid + it * 256;
        int d = c >> 3, nc = c & 7;
        ushort4 o0, o1;
        o0.x = tile[nc * 8 + 0][d]; o0.y = tile[nc * 8 + 1][d];
        o0.z = tile[nc * 8 + 2][d]; o0.w = tile[nc * 8 + 3][d];
        o1.x = tile[nc * 8 + 4][d]; o1.y = tile[nc * 8 + 5][d];
        o1.z = tile[nc * 8 + 6][d]; o1.w = tile[nc * 8 + 7][d];
        unsigned short* dst = &vt[((size_t)bh * 64 + d) * SEQ + nt * 64 + nc * 8];
        *reinterpret_cast<ushort4*>(dst)     = o0;
        *reinterpret_cast<ushort4*>(dst + 4) = o1;
    }
}

// Flash attention, no-max softmax (scores bounded after scale/log2e fold).
// Round-6 structure (166us, 0 conflicts) + two changes:
//  1. T12: P-exchange via permlane32_swap (VALU) instead of shfl_xor (LDS
//     bpermute) -- removes 64 bpermutes + 64 cndmasks per block-tile from
//     the PV dependency chain.
//  2. T1: XCD-locality block swizzle -- all 32 q-blocks of a bh land on one
//     XCD (3 bh x 1MB K/V < 4MB L2), staging hits local L2.
// 4 waves / 256 threads; q = lane&31 lane-local throughout.
__global__ __launch_bounds__(256) void attn_kernel(
    const unsigned short* __restrict__ qg,
    const unsigned short* __restrict__ kg,
    const unsigned short* __restrict__ vtg,
    unsigned short* __restrict__ attnout)
{
    __shared__ unsigned short shK[64][72];   // [kv][d]
    __shared__ unsigned short shV[64][72];   // [d][kv]  (V^T)

    // XCD swizzle: consecutive blockIdx round-robin across 8 XCDs; give each
    // XCD 3 whole bh's. wg = 0..767; xcd = wg&7 -> bh in [xcd*3, xcd*3+3).
    const int wg   = blockIdx.x;
    const int xcd  = wg & 7;
    const int slot = wg >> 3;            // 0..95
    const int bh   = xcd * 3 + (slot >> 5);
    const int qblk = slot & 31;
    const int b    = bh / HEADS;
    const int h    = bh % HEADS;

    const int tid  = threadIdx.x;
    const int lane = tid & 63;
    const int wid  = tid >> 6;
    const int l31  = lane & 31;
    const int hi   = lane >> 5;

    // Q fragments (B operand, col=q=l31, k = d0*16 + hi*8 + j)
    bf16x8 qf[4];
    {
        const unsigned short* qrow =
            qg + ((size_t)bh * SEQ + qblk * 128 + wid * 32 + l31) * 64 + hi * 8;
        #pragma unroll
        for (int d0 = 0; d0 < 4; ++d0)
            qf[d0] = *reinterpret_cast<const bf16x8*>(qrow + d0 * 16);
    }

    f32x16 ot[2];
    #pragma unroll
    for (int r = 0; r < 16; ++r) { ot[0][r] = 0.f; ot[1][r] = 0.f; }
    float l_lane = 0.f;

    const unsigned short* kbase = kg  + (size_t)bh * SEQ * 64;
    const unsigned short* vbase = vtg + (size_t)bh * 64 * SEQ;

    for (int kt = 0; kt < SEQ / 64; ++kt) {
        __syncthreads();
        #pragma unroll
        for (int it = 0; it < 2; ++it) {
            int c = tid + it * 256;
            int row = c >> 3, colc = c & 7;
            *reinterpret_cast<uint4*>(&shK[row][colc * 8]) =
                *reinterpret_cast<const uint4*>(&kbase[(size_t)(kt * 64 + row) * 64 + colc * 8]);
            *reinterpret_cast<uint4*>(&shV[row][colc * 8]) =
                *reinterpret_cast<const uint4*>(&vbase[(size_t)row * SEQ + kt * 64 + colc * 8]);
        }
        __syncthreads();

        // ---- S^T = K * Q^T (exp2 domain: scale folded into Q) ----
        f32x16 st0, st1;
        #pragma unroll
        for (int r = 0; r < 16; ++r) { st0[r] = 0.f; st1[r] = 0.f; }
        #pragma unroll
        for (int d0 = 0; d0 < 4; ++d0) {
            bf16x8 kf0 = *reinterpret_cast<const bf16x8*>(&shK[l31][d0 * 16 + hi * 8]);
            bf16x8 kf1 = *reinterpret_cast<const bf16x8*>(&shK[32 + l31][d0 * 16 + hi * 8]);
            st0 = __builtin_amdgcn_mfma_f32_32x32x16_bf16(kf0, qf[d0], st0, 0, 0, 0);
            st1 = __builtin_amdgcn_mfma_f32_32x32x16_bf16(kf1, qf[d0], st1, 0, 0, 0);
        }

        // ---- P = exp2(S), no max shift (scores bounded); pack bf16 pairs ----
        float s0 = 0.f, s1 = 0.f, s2 = 0.f, s3 = 0.f;
        unsigned cp0[8], cp1[8];
        #pragma unroll
        for (int t = 0; t < 8; ++t) {
            float pa = __builtin_amdgcn_exp2f(st0[2 * t]);
            float pb = __builtin_amdgcn_exp2f(st0[2 * t + 1]);
            float pc = __builtin_amdgcn_exp2f(st1[2 * t]);
            float pd = __builtin_amdgcn_exp2f(st1[2 * t + 1]);
            s0 += pa; s1 += pb; s2 += pc; s3 += pd;
            cp0[t] = pkbf(pa, pb);
            cp1[t] = pkbf(pc, pd);
        }
        l_lane += (s0 + s1) + (s2 + s3);

        // ---- O^T += V^T * P^T; B-frag via permlane32_swap (T12, guide §5.5):
        // s = swap(cp[i], cp[i+2]) exchanges the halves so that both s.x and
        // s.y are usable B-frag words (one swap fills two output words).
        #pragma unroll
        for (int cb = 0; cb < 2; ++cb) {
            #pragma unroll
            for (int kk = 0; kk < 2; ++kk) {
                unsigned c0 = cb ? cp1[4 * kk + 0] : cp0[4 * kk + 0];
                unsigned c1 = cb ? cp1[4 * kk + 1] : cp0[4 * kk + 1];
                unsigned c2 = cb ? cp1[4 * kk + 2] : cp0[4 * kk + 2];
                unsigned c3 = cb ? cp1[4 * kk + 3] : cp0[4 * kk + 3];
                u32x2 s = __builtin_amdgcn_permlane32_swap(c0, c2, false, false);
                u32x2 t = __builtin_amdgcn_permlane32_swap(c1, c3, false, false);
                union { unsigned uu[4]; bf16x8 v; } pu;
                pu.uu[0] = s.x;   // k = 8hi+0,1
                pu.uu[1] = t.x;   // k = 8hi+2,3
                pu.uu[2] = s.y;   // k = 8hi+4,5
                pu.uu[3] = t.y;   // k = 8hi+6,7
                #pragma unroll
                for (int df = 0; df < 2; ++df) {
                    bf16x8 vf = *reinterpret_cast<const bf16x8*>(
                        &shV[df * 32 + l31][cb * 32 + kk * 16 + hi * 8]);
                    ot[df] = __builtin_amdgcn_mfma_f32_32x32x16_bf16(vf, pu.v, ot[df], 0, 0, 0);
                }
            }
        }
    }

    // ---- epilogue: O[q][d] = O^T[d][q] / l, q = l31 lane-local ----
    float l_all = l_lane + __shfl_xor(l_lane, 32);
    float invl = 1.0f / l_all;
    int n = qblk * 128 + wid * 32 + l31;
    unsigned short* orow = attnout + ((size_t)(b * SEQ + n)) * INNER + h * 64;
    #pragma unroll
    for (int df = 0; df < 2; ++df) {
        #pragma unroll
        for (int t = 0; t < 4; ++t) {
            unsigned w0 = pkbf(ot[df][4 * t]     * invl, ot[df][4 * t + 1] * invl);
            unsigned w1 = pkbf(ot[df][4 * t + 2] * invl, ot[df][4 * t + 3] * invl);
            unsigned long long pk = (unsigned long long)w0 | ((unsigned long long)w1 << 32);
            *reinterpret_cast<unsigned long long*>(orow + df * 32 + t * 8 + hi * 4) = pk;
        }
    }
}

extern "C" void kernel_launch(void* const* d_in, const int* in_sizes, int n_in,
                              void* d_out, int out_size, void* d_ws, size_t ws_size,
                              hipStream_t stream)
{
    const float* x      = (const float*)d_in[0];
    const float* w_qkv  = (const float*)d_in[1];
    const float* w_out  = (const float*)d_in[2];
    const float* b_out  = (const float*)d_in[3];
    const float* scale  = (const float*)d_in[4];
    float* out = (float*)d_out;
    char* ws = (char*)d_ws;

    unsigned short* xb    = (unsigned short*)(ws);                 // 12,582,912
    unsigned short* wqkvb = (unsigned short*)(ws + 12582912);      //  3,538,944
    unsigned short* woutb = (unsigned short*)(ws + 16121856);      //  1,179,648
    unsigned short* attnb = (unsigned short*)(ws + 17301504);      // 12,582,912
    unsigned short* qb    = (unsigned short*)(ws + 29884416);      // 12,582,912
    unsigned short* kb    = (unsigned short*)(ws + 42467328);      // 12,582,912
    unsigned short* vtb   = (unsigned short*)(ws + 55050240);      // 12,582,912
    unsigned short* qkvb  = (unsigned short*)(ws + 67633152);      // 37,748,736

    cast_f32_bf16<<<6144, 256, 0, stream>>>(x, xb, 6291456);
    cast_f32_bf16<<<1728, 256, 0, stream>>>(w_qkv, wqkvb, 1769472);
    cast_f32_bf16<<<576, 256, 0, stream>>>(w_out, woutb, 589824);

    gemm_bt_kernel<true><<<dim3(64, 18), 256, 0, stream>>>(xb, wqkvb, qkvb, nullptr, ROWS, NQKV, DIMX);

    normalize_kernel<<<2048, 256, 0, stream>>>(qkvb, scale, qb, kb);
    vtrans_kernel<<<dim3(BATCH * HEADS, SEQ / 64), 256, 0, stream>>>(qkvb, vtb);

    attn_kernel<<<768, 256, 0, stream>>>(qb, kb, vtb, attnb);

    gemm_bt_kernel<false><<<dim3(64, 6), 256, 0, stream>>>(attnb, woutb, out, b_out, ROWS, INNER, INNER);
}